// Round 7
// baseline (114.565 us; speedup 1.0000x reference)
//
#include <hip/hip_runtime.h>
#include <hip/hip_bf16.h>

// Problem constants (fixed by the reference's setup_inputs).
constexpr int N_NODES  = 100000;
constexpr int BATCH    = 256;
constexpr int NUM_RELS = 200;
constexpr int VEC      = 300;
constexpr int DIM      = 32;
constexpr int MODES    = 6;

constexpr int BLOCK        = 1024;                    // 16 waves: one-round edge scan
constexpr int BM_WORDS     = (N_NODES + 31) / 32;     // 3125 words = 12.5 KB (LDS)
constexpr int RELS_PER_BLK = 32;                      // one rel per 32-lane group
constexpr int NRB          = (NUM_RELS + RELS_PER_BLK - 1) / RELS_PER_BLK; // 7 (last partial)
constexpr int EDGE_BLKS    = 256;                     // one list segment per edge block
constexpr int HASHN        = 1024;                    // LDS hash slots (load factor 0.5)
constexpr unsigned HEMPTY  = 0xFFFFFFFFu;
constexpr int CAP          = 128;                     // codes/segment: active segs Poisson(~41)
constexpr int MAXM         = 512;                     // per-b match buffer in k_final

// ---- dtype-generic scalar load ---------------------------------------------
template <typename T> __device__ __forceinline__ float ldf(const void* p, int i);
template <> __device__ __forceinline__ float ldf<float>(const void* p, int i) {
    return ((const float*)p)[i];
}
template <> __device__ __forceinline__ float ldf<__hip_bfloat16>(const void* p, int i) {
    return __bfloat162float(((const __hip_bfloat16*)p)[i]);
}

// ---- per-block bf16-vs-fp32 detect (one ballot on wave 0) ------------------
__device__ __forceinline__ void detect_dtype(const void* rel_vectors, int* sflag) {
    const int tid = threadIdx.x;
    if (tid < 64) {
        unsigned short p = ((const unsigned short*)rel_vectors)[tid];
        unsigned long long mk = __ballot(((p >> 7) & 0xFF) > 140);
        if (tid == 0) *sflag = (mk == 0ull);
    }
    __syncthreads();
}

// ---- LDS hash: node id -> packed (head_b+1 | (tail_b+1)<<16) ---------------
__device__ __forceinline__ void hinsert(unsigned* hkey, unsigned* hval, int node, unsigned v) {
    unsigned h = ((unsigned)node * 2654435761u) >> 22;   // top 10 bits
    for (;;) {
        unsigned prev = atomicCAS(&hkey[h], HEMPTY, (unsigned)node);
        if (prev == HEMPTY || prev == (unsigned)node) { atomicOr(&hval[h], v); return; }
        h = (h + 1) & (HASHN - 1);
    }
}
__device__ __forceinline__ unsigned hlookup(const unsigned* hkey, const unsigned* hval, int node) {
    unsigned h = ((unsigned)node * 2654435761u) >> 22;
    for (;;) {
        const unsigned k = hkey[h];
        if (k == (unsigned)node) return hval[h];
        if (k == HEMPTY) return 0u;
        h = (h + 1) & (HASHN - 1);
    }
}

// ---- rel phase: E_rel[r] = mlp2(rel_vectors[r]); Y_rel[m][r] = E_rel[r]@reld_W[m]+reld_b[m]
// 32 groups x 32 lanes per 1024-thread block; tail block clamps r (redundant
// compute on r=199, stores predicated) so no divergent barrier hazard.
// Plain stores: k_final runs after the kernel boundary (coherence for free).
template <typename T>
__device__ __forceinline__ void rel_body(const void* rel_vectors, const void* W1, const void* b1,
                                         const void* W2, const void* b2,
                                         const void* reld_W, const void* reld_b,
                                         float* E_rel, float* Y_rel,
                                         float (*rv)[VEC], float (*e1)[DIM], float (*e2)[DIM],
                                         int r0) {
    const int tid = threadIdx.x;
    const int g = tid >> 5, d = tid & 31;
    const int r = r0 + g;
    const bool live = (r < NUM_RELS);
    const int rc = live ? r : (NUM_RELS - 1);    // clamped for loads/compute
    for (int v = d; v < VEC; v += 32) rv[g][v] = ldf<T>(rel_vectors, rc * VEC + v);
    __syncthreads();
    float acc = ldf<T>(b1, d);
    for (int v = 0; v < VEC; ++v) acc += rv[g][v] * ldf<T>(W1, v * DIM + d);
    e1[g][d] = acc;
    __syncthreads();
    float a2 = ldf<T>(b2, d);
    for (int k = 0; k < DIM; ++k) a2 += e1[g][k] * ldf<T>(W2, k * DIM + d);
    e2[g][d] = a2;
    if (live) E_rel[r * DIM + d] = a2;
    __syncthreads();
    for (int m = 0; m < MODES; ++m) {
        float y = ldf<T>(reld_b, m * DIM + d);
        for (int k = 0; k < DIM; ++k) y += e2[g][k] * ldf<T>(reld_W, (m * DIM + k) * DIM + d);
        if (live) Y_rel[(m * NUM_RELS + r) * DIM + d] = y;
    }
}

// ---- per-b epilogue math ---------------------------------------------------
template <typename T>
__device__ __forceinline__ void epilogue_math(const float* cat,
                                              const void* conc_W, const void* conc_b,
                                              const void* fc_W, const void* fc_b,
                                              void* out, int b) {
    const int tid = threadIdx.x;
    if (tid < DIM) {
        float h = ldf<T>(conc_b, tid);
        for (int k = 0; k < 2 * DIM; ++k) h += cat[k] * ldf<T>(conc_W, k * DIM + tid);
        h = fmaxf(h, 0.f);
        float n2 = h * h;
        #pragma unroll
        for (int off = 16; off >= 1; off >>= 1) n2 += __shfl_xor(n2, off);
        const float g = h / fmaxf(sqrtf(n2), 1e-12f);
        float pr = g * ldf<T>(fc_W, tid);
        #pragma unroll
        for (int off = 16; off >= 1; off >>= 1) pr += __shfl_xor(pr, off);
        if (tid == 0) {
            const float o = pr + ldf<T>(fc_b, 0);
            if constexpr (sizeof(T) == 2) ((__hip_bfloat16*)out)[b] = __float2bfloat16(o);
            else                          ((float*)out)[b] = o;
        }
    }
}

// ---- K1: rel MLP + edge scan, per-edge-block list (NO pre-zeroed state) ----
// vs round 6: the per-b bucket scheme needed a zeroed bcnt => an extra
// hipMemsetAsync dispatch (+gap) per iteration. This version writes
// listcnt[eb] UNCONDITIONALLY (every consumed word is written first), so the
// memset dispatch disappears. Codes stage in LDS obuf (LDS atomics, not ~5K
// device-scope atomicAdds) and flush once, transposed (list[i*256+eb]) so
// k_final's scan reads coalesced rounds from cache.
// bid < NRB           : rel MLP (32 rels/block).
// bid in [NRB, +EDGE) : 1024-thread edge scan — one int4-pair per thread
//                       (262144 slots >= n4=125000). Blocks whose slice is
//                       empty (eb*1024 >= ceil(n_edges/4)) write listcnt=0
//                       and exit before any LDS work.
struct EdgeSmem {
    unsigned bm[BM_WORDS];
    unsigned hkey[HASHN];
    unsigned hval[HASHN];
    unsigned obuf[CAP];
    int ocnt;
};
struct RelSmem {
    float rv[RELS_PER_BLK][VEC];
    float e1[RELS_PER_BLK][DIM];
    float e2[RELS_PER_BLK][DIM];
    int sflag;
};

__global__ __launch_bounds__(BLOCK) void k_main(
        const int* __restrict__ edge_src, const int* __restrict__ edge_dst,
        const int* __restrict__ edge_type,
        const int* __restrict__ head_ids, const int* __restrict__ tail_ids,
        const void* rel_vectors, const void* W1, const void* b1,
        const void* W2, const void* b2, const void* reld_W, const void* reld_b,
        unsigned* __restrict__ list, unsigned* __restrict__ listcnt,
        float* __restrict__ E_rel, float* __restrict__ Y_rel, int n_edges) {
    union SmemU { RelSmem rel; EdgeSmem edge; };
    __shared__ SmemU s;
    const int bid = blockIdx.x, tid = threadIdx.x;

    if (bid < NRB) {
        detect_dtype(rel_vectors, &s.rel.sflag);
        const int r0 = bid * RELS_PER_BLK;
        if (s.rel.sflag)
            rel_body<__hip_bfloat16>(rel_vectors, W1, b1, W2, b2, reld_W, reld_b,
                                     E_rel, Y_rel, s.rel.rv, s.rel.e1, s.rel.e2, r0);
        else
            rel_body<float>(rel_vectors, W1, b1, W2, b2, reld_W, reld_b,
                            E_rel, Y_rel, s.rel.rv, s.rel.e1, s.rel.e2, r0);
        return;
    }

    // ---- edge block ----
    const int eb = bid - NRB;
    const int n4c = (n_edges + 3) >> 2;           // int4-pairs incl. remainder slot
    if (eb * BLOCK >= n4c) {                      // empty slice: no LDS work at all
        if (tid == 0) listcnt[eb] = 0u;
        return;
    }
    for (int i = tid; i < BM_WORDS; i += BLOCK) s.edge.bm[i] = 0u;
    for (int i = tid; i < HASHN; i += BLOCK) { s.edge.hkey[i] = HEMPTY; s.edge.hval[i] = 0u; }
    if (tid == 0) s.edge.ocnt = 0;
    __syncthreads();
    if (tid < BATCH) {
        const int h = head_ids[tid], t = tail_ids[tid];
        atomicOr(&s.edge.bm[h >> 5], 1u << (h & 31));
        atomicOr(&s.edge.bm[t >> 5], 1u << (t & 31));
        hinsert(s.edge.hkey, s.edge.hval, h, (unsigned)(tid + 1));
        hinsert(s.edge.hkey, s.edge.hval, t, (unsigned)(tid + 1) << 16);
    }
    __syncthreads();

    auto emit = [&](unsigned code) {
        const int idx = atomicAdd(&s.edge.ocnt, 1);
        if (idx < CAP) s.edge.obuf[idx] = code;
    };
    auto classify = [&](int sn, int dn, unsigned bs, unsigned bd, int e) {
        const unsigned t = (unsigned)edge_type[e];
        const unsigned ps = bs ? hlookup(s.edge.hkey, s.edge.hval, sn) : 0u;
        const unsigned pd = bd ? hlookup(s.edge.hkey, s.edge.hval, dn) : 0u;
        const int hbs = (int)(ps & 0xFFFFu) - 1, tbs = (int)(ps >> 16) - 1;
        const int hbd = (int)(pd & 0xFFFFu) - 1, tbd = (int)(pd >> 16) - 1;
        const bool m5 = (hbs >= 0) && (hbs == tbd);
        const bool m6 = (hbd >= 0) && (hbd == tbs);
        if (hbd >= 0)        emit(((m6 ? 5u : 0u) * BATCH + (unsigned)hbd) * NUM_RELS + t);
        if (hbs >= 0)        emit(((m5 ? 4u : 1u) * BATCH + (unsigned)hbs) * NUM_RELS + t);
        if (tbd >= 0 && !m5) emit((2u * BATCH + (unsigned)tbd) * NUM_RELS + t);
        if (tbs >= 0 && !m6) emit((3u * BATCH + (unsigned)tbs) * NUM_RELS + t);
    };

    // one int4-pair per thread: 262144 thread-slots cover n4=125000
    const int n4 = n_edges >> 2;
    const int sstr = EDGE_BLKS * BLOCK;
    const int et = eb * BLOCK + tid;
    const int4* src4 = (const int4*)edge_src;
    const int4* dst4 = (const int4*)edge_dst;
    for (int i = et; i < n4; i += sstr) {         // executes <= 1 iteration here
        const int4 s4 = src4[i];
        const int4 d4 = dst4[i];
        #pragma unroll
        for (int j = 0; j < 4; ++j) {
            const int sn = (&s4.x)[j];
            const int dn = (&d4.x)[j];
            const unsigned bs = (s.edge.bm[sn >> 5] >> (sn & 31)) & 1u;
            const unsigned bd = (s.edge.bm[dn >> 5] >> (dn & 31)) & 1u;
            if (!(bs | bd)) continue;            // ~99% of edges: 2 LDS reads only
            classify(sn, dn, bs, bd, i * 4 + j);
        }
    }
    const int rem = n_edges & 3;
    if (et < rem) {
        const int e = n4 * 4 + et;
        const int sn = edge_src[e], dn = edge_dst[e];
        const unsigned bs = (s.edge.bm[sn >> 5] >> (sn & 31)) & 1u;
        const unsigned bd = (s.edge.bm[dn >> 5] >> (dn & 31)) & 1u;
        if (bs | bd) classify(sn, dn, bs, bd, e);
    }
    __syncthreads();
    const int oc = min(s.edge.ocnt, CAP);
    if (tid == 0) listcnt[eb] = (unsigned)oc;    // unconditional: no pre-zero needed
    for (int i = tid; i < oc; i += BLOCK) list[i * EDGE_BLKS + eb] = s.edge.obuf[i];
}

// ---- K2: per-b epilogue, 1024 threads, 4-way-parallel segment scan ---------
// thread tid covers segment (tid&255), rounds (tid>>8)+4k. Each round is a
// coalesced cached load (list is 128KB, L2/L3-resident after first touch);
// loads are address-independent so the 16 waves pipeline them.
__global__ __launch_bounds__(BLOCK) void k_final(
        const unsigned* __restrict__ list, const unsigned* __restrict__ listcnt,
        const float* __restrict__ E_rel, const float* __restrict__ Y_rel,
        const int* __restrict__ rel_labels, const void* rel_vectors,
        const void* conc_W, const void* conc_b, const void* fc_W, const void* fc_b,
        void* out) {
    __shared__ float    accf[MODES][DIM];
    __shared__ float    totf[MODES];
    __shared__ unsigned mbuf[MAXM];
    __shared__ int      mcnt;
    __shared__ float    cat[2 * DIM];
    __shared__ int      sflag;
    const int b = blockIdx.x, tid = threadIdx.x;

    for (int i = tid; i < MODES * DIM; i += BLOCK) ((float*)accf)[i] = 0.f;
    if (tid < MODES) totf[tid] = 0.f;
    if (tid == 0) mcnt = 0;
    const int seg = tid & (EDGE_BLKS - 1);
    const int r0  = tid >> 8;                    // 0..3
    const int c   = (int)listcnt[seg];
    detect_dtype(rel_vectors, &sflag);           // includes __syncthreads

    // 4-way parallel scan over this segment's codes; filter bb == b
    for (int i = r0; i < c; i += 4) {
        const unsigned code = list[i * EDGE_BLKS + seg];
        const int bb = (int)((code / NUM_RELS) % BATCH);
        if (bb == b) {
            const int k = atomicAdd(&mcnt, 1);
            if (k < MAXM) mbuf[k] = code;
        }
    }
    __syncthreads();

    // accumulate matched Y_rel rows; 32 half-wave groups over matches (cached)
    const int mc = min(mcnt, MAXM);
    const int d = tid & 31;
    for (int j = tid >> 5; j < mc; j += BLOCK / 32) {
        const unsigned code = mbuf[j];
        const int m = (int)(code / (NUM_RELS * BATCH));
        const int t = (int)(code % NUM_RELS);
        atomicAdd(&accf[m][d], Y_rel[(m * NUM_RELS + t) * DIM + d]);
        if (d == 0) atomicAdd(&totf[m], 1.f);
    }
    __syncthreads();

    if (tid < DIM) {
        float rn = 0.f;
        for (int m = 0; m < MODES; ++m) rn += accf[m][tid] / (totf[m] + 1e-30f);
        cat[tid] = rn / (float)MODES;
        cat[DIM + tid] = E_rel[rel_labels[b] * DIM + tid];
    }
    __syncthreads();
    if (sflag) epilogue_math<__hip_bfloat16>(cat, conc_W, conc_b, fc_W, fc_b, out, b);
    else       epilogue_math<float>(cat, conc_W, conc_b, fc_W, fc_b, out, b);
}

extern "C" void kernel_launch(void* const* d_in, const int* in_sizes, int n_in,
                              void* d_out, int out_size, void* d_ws, size_t ws_size,
                              hipStream_t stream) {
    const int* edge_src   = (const int*)d_in[0];
    const int* edge_dst   = (const int*)d_in[1];
    const int* edge_type  = (const int*)d_in[2];
    const int* head_ids   = (const int*)d_in[3];
    const int* tail_ids   = (const int*)d_in[4];
    const int* rel_labels = (const int*)d_in[5];
    const void* rel_vectors = d_in[6];
    const void* W1     = d_in[7];
    const void* b1     = d_in[8];
    const void* W2     = d_in[9];
    const void* b2     = d_in[10];
    const void* reld_W = d_in[11];
    const void* reld_b = d_in[12];
    const void* conc_W = d_in[13];
    const void* conc_b = d_in[14];
    const void* fc_W   = d_in[15];
    const void* fc_b   = d_in[16];

    const int n_edges = in_sizes[0];

    // workspace layout (~310 KB of ws): every consumed word is written first
    // (listcnt unconditional; list below listcnt[eb]; E_rel/Y_rel by rel
    // blocks) => NO memset dispatch needed despite per-iteration poisoning.
    unsigned* list    = (unsigned*)d_ws;                 // CAP * EDGE_BLKS (transposed, 128 KB)
    unsigned* listcnt = list + EDGE_BLKS * CAP;          // EDGE_BLKS
    float*    E_rel   = (float*)(listcnt + EDGE_BLKS);   // NUM_RELS*DIM
    float*    Y_rel   = E_rel + NUM_RELS * DIM;          // MODES*NUM_RELS*DIM

    k_main<<<NRB + EDGE_BLKS, BLOCK, 0, stream>>>(
        edge_src, edge_dst, edge_type, head_ids, tail_ids,
        rel_vectors, W1, b1, W2, b2, reld_W, reld_b,
        list, listcnt, E_rel, Y_rel, n_edges);
    k_final<<<BATCH, BLOCK, 0, stream>>>(
        list, listcnt, E_rel, Y_rel, rel_labels, rel_vectors,
        conc_W, conc_b, fc_W, fc_b, d_out);
}